// Round 1
// baseline (784.830 us; speedup 1.0000x reference)
//
#include <hip/hip_runtime.h>

#define D 133
#define DP 136        // padded row stride (floats), 16B-aligned rows
#define WSTR 140      // LDS stride for W^T (breaks bank pattern, float4-aligned)
#define NCG 34        // column groups of 4 (covers 136)
#define NGRAPH 256

// ---------- pad x into stride-DP buffer, zero cnt ----------
__global__ void k_pad(const float* __restrict__ x, float* __restrict__ xpad,
                      int* __restrict__ cnt, int N) {
    int i = blockIdx.x * 256 + threadIdx.x;
    int total = N * DP;
    if (i < total) {
        int m = i / DP, c = i - m * DP;
        xpad[i] = (c < D) ? x[(size_t)m * D + c] : 0.f;
    }
    if (i < N) cnt[i] = 0;
}

// ---------- in-degree histogram (real edges only) ----------
__global__ void k_count(const int* __restrict__ dst, int* __restrict__ cnt, int E) {
    int i = blockIdx.x * 256 + threadIdx.x;
    if (i < E) atomicAdd(&cnt[dst[i]], 1);
}

// ---------- single-block exclusive scan -> row_off, cursor; dinv = rsqrt(deg+1) ----------
__global__ __launch_bounds__(1024) void k_scan(const int* __restrict__ cnt,
                                               int* __restrict__ row_off,
                                               int* __restrict__ cursor,
                                               float* __restrict__ dinv, int N) {
    __shared__ int sums[1024];
    int t = threadIdx.x;
    int CH = (N + 1023) >> 10;
    int beg = t * CH, end = beg + CH; if (end > N) end = N; if (beg > N) beg = N;
    int s = 0;
    for (int i = beg; i < end; ++i) s += cnt[i];
    sums[t] = s;
    __syncthreads();
    for (int off = 1; off < 1024; off <<= 1) {
        int v = (t >= off) ? sums[t - off] : 0;
        __syncthreads();
        sums[t] += v;
        __syncthreads();
    }
    int run = sums[t] - s;  // exclusive prefix for this thread's chunk
    for (int i = beg; i < end; ++i) {
        int c = cnt[i];
        row_off[i] = run;
        cursor[i]  = run;
        dinv[i] = rsqrtf((float)(c + 1));   // +1 self-loop; always > 0
        run += c;
    }
    if (t == 1023) row_off[N] = sums[1023];
}

// ---------- scatter edges into CSR slots ----------
__global__ void k_fill(const int* __restrict__ src, const int* __restrict__ dst,
                       int* __restrict__ cursor, int* __restrict__ ssrc, int E) {
    int i = blockIdx.x * 256 + threadIdx.x;
    if (i < E) {
        int slot = atomicAdd(&cursor[dst[i]], 1);
        ssrc[slot] = src[i];
    }
}

// ---------- graph boundary via binary search (batch is sorted) ----------
__global__ void k_gstart(const int* __restrict__ batch, int* __restrict__ gstart, int N) {
    int g = blockIdx.x * 256 + threadIdx.x;
    if (g > NGRAPH) return;
    int lo = 0, hi = N;
    while (lo < hi) {
        int mid = (lo + hi) >> 1;
        if (batch[mid] < g) lo = mid + 1; else hi = mid;
    }
    gstart[g] = lo;
}

// ---------- Y[m, n] = sum_k X[m,k] * W[k,n]; X stride DP (padded, pads harmless) ----------
__global__ __launch_bounds__(256) void k_mm(const float* __restrict__ X,
                                            const float* __restrict__ W,
                                            float* __restrict__ Y, int N) {
    __shared__ float WT[67 * WSTR];          // 36.6 KB: half the columns, transposed
    int half = blockIdx.x & 1;
    int n0 = half ? 67 : 0;
    // load + transpose this half of W (guard col >= D -> 0)
    for (int i = threadIdx.x; i < 67 * D; i += 256) {
        int k = i / 67;
        int nl = i - k * 67;
        int n = n0 + nl;
        WT[nl * WSTR + k] = (n < D) ? W[(size_t)k * D + n] : 0.f;
    }
    for (int i = threadIdx.x; i < 67 * (WSTR - D); i += 256) {  // zero k pads 133..139
        int k = D + i / 67;
        int nl = i - (i / 67) * 67;
        WT[nl * WSTR + k] = 0.f;
    }
    __syncthreads();

    int mq = N >> 2;                 // 4 rows per thread
    int jobs = mq * 67;
    int stride = (gridDim.x >> 1) * 256;
    for (int j = (blockIdx.x >> 1) * 256 + threadIdx.x; j < jobs; j += stride) {
        int nl = j % 67;
        int mb = (j / 67) << 2;
        const float4* wr = (const float4*)(WT + nl * WSTR);
        const float4* x0 = (const float4*)(X + (size_t)mb * DP);
        const float4* x1 = x0 + (DP >> 2);
        const float4* x2 = x1 + (DP >> 2);
        const float4* x3 = x2 + (DP >> 2);
        float a0 = 0.f, a1 = 0.f, a2 = 0.f, a3 = 0.f;
        for (int k4 = 0; k4 < (DP >> 2); ++k4) {
            float4 w = wr[k4];
            float4 v0 = x0[k4], v1 = x1[k4], v2 = x2[k4], v3 = x3[k4];
            a0 += v0.x * w.x + v0.y * w.y + v0.z * w.z + v0.w * w.w;
            a1 += v1.x * w.x + v1.y * w.y + v1.z * w.z + v1.w * w.w;
            a2 += v2.x * w.x + v2.y * w.y + v2.z * w.z + v2.w * w.w;
            a3 += v3.x * w.x + v3.y * w.y + v3.z * w.z + v3.w * w.w;
        }
        int n = n0 + nl;
        if (n < D) {
            size_t o = (size_t)mb * DP + n;
            Y[o] = a0; Y[o + DP] = a1; Y[o + 2 * DP] = a2; Y[o + 3 * DP] = a3;
        }
    }
}

// ---------- normalized aggregation + bias + relu ----------
// out[d] = relu( dinv[d] * ( sum_{s in in(d)} dinv[s]*H[s] + dinv[d]*H[d] ) + b )
__global__ void k_agg(const float* __restrict__ H, const float* __restrict__ bias,
                      const int* __restrict__ row_off, const int* __restrict__ ssrc,
                      const float* __restrict__ dinv, float* __restrict__ out, int N) {
    int idx = blockIdx.x * 256 + threadIdx.x;
    if (idx >= N * NCG) return;
    int node = idx / NCG;
    int cg = idx - node * NCG;
    int c = cg << 2;
    float di = dinv[node];
    float4 h0 = *(const float4*)(H + (size_t)node * DP + c);
    float4 acc;
    acc.x = di * h0.x; acc.y = di * h0.y; acc.z = di * h0.z; acc.w = di * h0.w;
    int e = row_off[node], e1 = row_off[node + 1];
    for (; e < e1; ++e) {
        int s = ssrc[e];
        float w = dinv[s];
        float4 hv = *(const float4*)(H + (size_t)s * DP + c);
        acc.x += w * hv.x; acc.y += w * hv.y; acc.z += w * hv.z; acc.w += w * hv.w;
    }
    float b0 = bias[c];
    float b1 = (c + 1 < D) ? bias[c + 1] : 0.f;
    float b2 = (c + 2 < D) ? bias[c + 2] : 0.f;
    float b3 = (c + 3 < D) ? bias[c + 3] : 0.f;
    float4 r;
    r.x = fmaxf(di * acc.x + b0, 0.f);
    r.y = fmaxf(di * acc.y + b1, 0.f);
    r.z = fmaxf(di * acc.z + b2, 0.f);
    r.w = fmaxf(di * acc.w + b3, 0.f);
    *(float4*)(out + (size_t)node * DP + c) = r;
}

// ---------- per-graph mean pool (one block per graph) ----------
__global__ void k_pool(const float* __restrict__ H, const int* __restrict__ gstart,
                       float* __restrict__ out) {
    int g = blockIdx.x;
    int t = threadIdx.x;
    if (t >= D) return;
    int s = gstart[g], e = gstart[g + 1];
    float acc = 0.f;
    for (int i = s; i < e; ++i) acc += H[(size_t)i * DP + t];
    float n = (float)(e - s);
    out[(size_t)g * D + t] = acc / fmaxf(n, 1.f);
}

extern "C" void kernel_launch(void* const* d_in, const int* in_sizes, int n_in,
                              void* d_out, int out_size, void* d_ws, size_t ws_size,
                              hipStream_t stream) {
    const float* x   = (const float*)d_in[0];
    const int* ei    = (const int*)d_in[1];
    const int* batch = (const int*)d_in[2];
    const float* W1  = (const float*)d_in[3];
    const float* b1  = (const float*)d_in[4];
    const float* W2  = (const float*)d_in[5];
    const float* b2  = (const float*)d_in[6];
    float* out = (float*)d_out;

    int N = in_sizes[0] / D;   // 50000
    int E = in_sizes[1] / 2;   // 800000
    const int* src = ei;
    const int* dst = ei + E;

    char* w = (char*)d_ws;
    float* xpad   = (float*)w; w += (size_t)N * DP * 4;
    float* bufA   = (float*)w; w += (size_t)N * DP * 4;
    float* bufB   = (float*)w; w += (size_t)N * DP * 4;
    float* dinv   = (float*)w; w += (size_t)N * 4;
    int* cnt      = (int*)w;   w += (size_t)N * 4;
    int* row_off  = (int*)w;   w += (size_t)(N + 1) * 4;
    int* cursor   = (int*)w;   w += (size_t)N * 4;
    int* ssrc     = (int*)w;   w += (size_t)E * 4;
    int* gstart   = (int*)w;   w += (size_t)(NGRAPH + 1) * 4;

    k_pad   <<<(N * DP + 255) / 256, 256, 0, stream>>>(x, xpad, cnt, N);
    k_count <<<(E + 255) / 256, 256, 0, stream>>>(dst, cnt, E);
    k_scan  <<<1, 1024, 0, stream>>>(cnt, row_off, cursor, dinv, N);
    k_fill  <<<(E + 255) / 256, 256, 0, stream>>>(src, dst, cursor, ssrc, E);
    k_gstart<<<2, 256, 0, stream>>>(batch, gstart, N);

    k_mm    <<<1024, 256, 0, stream>>>(xpad, W1, bufA, N);
    k_agg   <<<(N * NCG + 255) / 256, 256, 0, stream>>>(bufA, b1, row_off, ssrc, dinv, bufB, N);
    k_mm    <<<1024, 256, 0, stream>>>(bufB, W2, bufA, N);
    k_agg   <<<(N * NCG + 255) / 256, 256, 0, stream>>>(bufA, b2, row_off, ssrc, dinv, bufB, N);
    k_pool  <<<NGRAPH, 192, 0, stream>>>(bufB, gstart, out);
}

// Round 3
// 500.146 us; speedup vs baseline: 1.5692x; 1.5692x over previous
//
#include <hip/hip_runtime.h>

#define D 133
#define DP 136        // padded row stride (floats), 16B-aligned rows
#define NCG 34        // column groups of 4 (covers 136)
#define NGRAPH 256
#define WS 72         // LDS stride (cols) per k-row of W half
#define HALF_COLS 68  // columns per k_mm half

__device__ __forceinline__ void fma4(float4& a, float s, const float4& w) {
    a.x = fmaf(s, w.x, a.x);
    a.y = fmaf(s, w.y, a.y);
    a.z = fmaf(s, w.z, a.z);
    a.w = fmaf(s, w.w, a.w);
}

// ---------- pad x into stride-DP buffer, zero cnt ----------
__global__ void k_pad(const float* __restrict__ x, float* __restrict__ xpad,
                      int* __restrict__ cnt, int N) {
    int i = blockIdx.x * 256 + threadIdx.x;
    int total = N * DP;
    if (i < total) {
        int m = i / DP, c = i - m * DP;
        xpad[i] = (c < D) ? x[(size_t)m * D + c] : 0.f;
    }
    if (i < N) cnt[i] = 0;
}

// ---------- in-degree histogram (real edges only) ----------
__global__ void k_count(const int* __restrict__ dst, int* __restrict__ cnt, int E) {
    int i = blockIdx.x * 256 + threadIdx.x;
    if (i < E) atomicAdd(&cnt[dst[i]], 1);
}

// ---------- phase A: per-1024-chunk block sums ----------
__global__ __launch_bounds__(256) void k_bsum(const int* __restrict__ cnt,
                                              int* __restrict__ bsum, int N) {
    __shared__ int wsum[4];
    int b = blockIdx.x, t = threadIdx.x;
    int i0 = b * 1024 + t * 4;
    int s = 0;
    #pragma unroll
    for (int j = 0; j < 4; ++j) { int i = i0 + j; if (i < N) s += cnt[i]; }
    #pragma unroll
    for (int off = 32; off >= 1; off >>= 1) s += __shfl_down(s, off, 64);
    if ((t & 63) == 0) wsum[t >> 6] = s;
    __syncthreads();
    if (t == 0) bsum[b] = wsum[0] + wsum[1] + wsum[2] + wsum[3];
}

// ---------- phase B+C: base via wave-reduce over bsum, in-block scan ----------
__global__ __launch_bounds__(256) void k_scan2(const int* __restrict__ cnt,
                                               const int* __restrict__ bsum,
                                               int* __restrict__ row_off,
                                               int* __restrict__ cursor,
                                               float* __restrict__ dinv,
                                               int nb, int N) {
    __shared__ int base_s;
    __shared__ int scan[256];
    int b = blockIdx.x, t = threadIdx.x;
    if (t < 64) {
        int v = (t < b && t < nb) ? bsum[t] : 0;   // nb <= 64
        #pragma unroll
        for (int off = 32; off >= 1; off >>= 1) v += __shfl_down(v, off, 64);
        if (t == 0) base_s = v;
    }
    int i0 = b * 1024 + t * 4;
    int c0 = 0, c1 = 0, c2 = 0, c3 = 0;
    if (i0 + 3 < N) { c0 = cnt[i0]; c1 = cnt[i0+1]; c2 = cnt[i0+2]; c3 = cnt[i0+3]; }
    else {
        if (i0 < N) c0 = cnt[i0];
        if (i0 + 1 < N) c1 = cnt[i0+1];
        if (i0 + 2 < N) c2 = cnt[i0+2];
        if (i0 + 3 < N) c3 = cnt[i0+3];
    }
    int s = c0 + c1 + c2 + c3;
    scan[t] = s;
    __syncthreads();
    for (int off = 1; off < 256; off <<= 1) {
        int v = (t >= off) ? scan[t - off] : 0;
        __syncthreads();
        scan[t] += v;
        __syncthreads();
    }
    int excl = base_s + scan[t] - s;
    int cc[4] = {c0, c1, c2, c3};
    #pragma unroll
    for (int j = 0; j < 4; ++j) {
        int idx = i0 + j;
        if (idx < N) {
            row_off[idx] = excl;
            cursor[idx]  = excl;
            dinv[idx] = rsqrtf((float)(cc[j] + 1));
            excl += cc[j];
            if (idx == N - 1) row_off[N] = excl;
        }
    }
}

// ---------- scatter edges into CSR slots; also store source weight ----------
__global__ void k_fill(const int* __restrict__ src, const int* __restrict__ dst,
                       int* __restrict__ cursor, const float* __restrict__ dinv,
                       int* __restrict__ ssrc, float* __restrict__ ssw, int E) {
    int i = blockIdx.x * 256 + threadIdx.x;
    if (i < E) {
        int s = src[i];
        int slot = atomicAdd(&cursor[dst[i]], 1);
        ssrc[slot] = s;
        ssw[slot] = dinv[s];
    }
}

// ---------- graph boundary via binary search (batch is sorted) ----------
__global__ void k_gstart(const int* __restrict__ batch, int* __restrict__ gstart, int N) {
    int g = blockIdx.x * 256 + threadIdx.x;
    if (g > NGRAPH) return;
    int lo = 0, hi = N;
    while (lo < hi) {
        int mid = (lo + hi) >> 1;
        if (batch[mid] < g) lo = mid + 1; else hi = mid;
    }
    gstart[g] = lo;
}

// ---------- Y[m,n] = sum_k X[m,k]*W[k,n]; 4x4 tile per thread ----------
// Block handles one column half (68 cols) of W in LDS: WL[k][cl], k=0..135.
__global__ __launch_bounds__(256) void k_mm(const float* __restrict__ X,
                                            const float* __restrict__ W,
                                            float* __restrict__ Y, int N) {
    __shared__ float WL[DP * WS];            // 136*72*4 = 38.25 KB
    int half = blockIdx.x & 1;
    int cbase = half * HALF_COLS;
    for (int i = threadIdx.x; i < DP * HALF_COLS; i += 256) {
        int k = i / HALF_COLS;
        int cl = i - k * HALF_COLS;
        int c = cbase + cl;
        WL[k * WS + cl] = (k < D && c < D) ? W[(size_t)k * D + c] : 0.f;
    }
    __syncthreads();

    int rows4 = N >> 2;
    int jobs = rows4 * 17;
    int jid = (blockIdx.x >> 1) * 256 + threadIdx.x;
    if (jid >= jobs) return;
    int cg = jid % 17;
    int rg = jid / 17;
    int c0 = cg << 2;            // local col within half
    size_t mb = (size_t)(rg << 2);

    const float4* x0 = (const float4*)(X + mb * DP);
    const float4* x1 = x0 + (DP >> 2);
    const float4* x2 = x1 + (DP >> 2);
    const float4* x3 = x2 + (DP >> 2);

    float4 a0 = {0,0,0,0}, a1 = {0,0,0,0}, a2 = {0,0,0,0}, a3 = {0,0,0,0};
    const float* wp = WL + c0;
    #pragma unroll 2
    for (int k4 = 0; k4 < (DP >> 2); ++k4) {
        float4 v0 = x0[k4], v1 = x1[k4], v2 = x2[k4], v3 = x3[k4];
        float4 wA = *(const float4*)(wp + (k4 * 4 + 0) * WS);
        float4 wB = *(const float4*)(wp + (k4 * 4 + 1) * WS);
        float4 wC = *(const float4*)(wp + (k4 * 4 + 2) * WS);
        float4 wD = *(const float4*)(wp + (k4 * 4 + 3) * WS);
        fma4(a0, v0.x, wA); fma4(a0, v0.y, wB); fma4(a0, v0.z, wC); fma4(a0, v0.w, wD);
        fma4(a1, v1.x, wA); fma4(a1, v1.y, wB); fma4(a1, v1.z, wC); fma4(a1, v1.w, wD);
        fma4(a2, v2.x, wA); fma4(a2, v2.y, wB); fma4(a2, v2.z, wC); fma4(a2, v2.w, wD);
        fma4(a3, v3.x, wA); fma4(a3, v3.y, wB); fma4(a3, v3.z, wC); fma4(a3, v3.w, wD);
    }
    size_t o = mb * DP + cbase + c0;         // always within padded row (<=135)
    *(float4*)(Y + o)          = a0;
    *(float4*)(Y + o + DP)     = a1;
    *(float4*)(Y + o + 2*DP)   = a2;
    *(float4*)(Y + o + 3*DP)   = a3;
}

// ---------- normalized aggregation + bias + relu ----------
// out[d] = relu( dinv[d]*( sum_in dinv[s]*H[s] + dinv[d]*H[d] ) + b )
__global__ void k_agg(const float* __restrict__ H, const float* __restrict__ bias,
                      const int* __restrict__ row_off, const int* __restrict__ ssrc,
                      const float* __restrict__ ssw, const float* __restrict__ dinv,
                      float* __restrict__ out, int N) {
    int idx = blockIdx.x * 256 + threadIdx.x;
    if (idx >= N * NCG) return;
    int node = idx / NCG;
    int cg = idx - node * NCG;
    int c = cg << 2;
    float di = dinv[node];
    float4 h0 = *(const float4*)(H + (size_t)node * DP + c);
    float4 acc;
    acc.x = di * h0.x; acc.y = di * h0.y; acc.z = di * h0.z; acc.w = di * h0.w;
    int e = row_off[node], e1 = row_off[node + 1];
    for (; e + 4 <= e1; e += 4) {
        int s0 = ssrc[e], s1 = ssrc[e+1], s2 = ssrc[e+2], s3 = ssrc[e+3];
        float w0 = ssw[e], w1 = ssw[e+1], w2 = ssw[e+2], w3 = ssw[e+3];
        float4 v0 = *(const float4*)(H + (size_t)s0 * DP + c);
        float4 v1 = *(const float4*)(H + (size_t)s1 * DP + c);
        float4 v2 = *(const float4*)(H + (size_t)s2 * DP + c);
        float4 v3 = *(const float4*)(H + (size_t)s3 * DP + c);
        fma4(acc, w0, v0); fma4(acc, w1, v1); fma4(acc, w2, v2); fma4(acc, w3, v3);
    }
    for (; e < e1; ++e) {
        int s = ssrc[e];
        float wv = ssw[e];
        float4 hv = *(const float4*)(H + (size_t)s * DP + c);
        fma4(acc, wv, hv);
    }
    float b0 = bias[c];
    float b1 = (c + 1 < D) ? bias[c + 1] : 0.f;
    float b2 = (c + 2 < D) ? bias[c + 2] : 0.f;
    float b3 = (c + 3 < D) ? bias[c + 3] : 0.f;
    float4 r;
    r.x = fmaxf(fmaf(di, acc.x, b0), 0.f);
    r.y = fmaxf(fmaf(di, acc.y, b1), 0.f);
    r.z = fmaxf(fmaf(di, acc.z, b2), 0.f);
    r.w = fmaxf(fmaf(di, acc.w, b3), 0.f);
    *(float4*)(out + (size_t)node * DP + c) = r;
}

// ---------- per-graph mean pool (one block per graph) ----------
__global__ void k_pool(const float* __restrict__ H, const int* __restrict__ gstart,
                       float* __restrict__ out) {
    int g = blockIdx.x;
    int t = threadIdx.x;
    if (t >= D) return;
    int s = gstart[g], e = gstart[g + 1];
    float acc = 0.f;
    for (int i = s; i < e; ++i) acc += H[(size_t)i * DP + t];
    float n = (float)(e - s);
    out[(size_t)g * D + t] = acc / fmaxf(n, 1.f);
}

extern "C" void kernel_launch(void* const* d_in, const int* in_sizes, int n_in,
                              void* d_out, int out_size, void* d_ws, size_t ws_size,
                              hipStream_t stream) {
    const float* x   = (const float*)d_in[0];
    const int* ei    = (const int*)d_in[1];
    const int* batch = (const int*)d_in[2];
    const float* W1  = (const float*)d_in[3];
    const float* b1  = (const float*)d_in[4];
    const float* W2  = (const float*)d_in[5];
    const float* b2  = (const float*)d_in[6];
    float* out = (float*)d_out;

    int N = in_sizes[0] / D;   // 50000
    int E = in_sizes[1] / 2;   // 800000
    const int* src = ei;
    const int* dst = ei + E;

    char* w = (char*)d_ws;
    float* xpad   = (float*)w; w += (size_t)N * DP * 4;
    float* bufA   = (float*)w; w += (size_t)N * DP * 4;
    float* bufB   = (float*)w; w += (size_t)N * DP * 4;
    float* dinv   = (float*)w; w += (size_t)N * 4;
    int* cnt      = (int*)w;   w += (size_t)N * 4;
    int* row_off  = (int*)w;   w += (size_t)(N + 1) * 4;
    int* cursor   = (int*)w;   w += (size_t)N * 4;
    int* ssrc     = (int*)w;   w += (size_t)E * 4;
    float* ssw    = (float*)w; w += (size_t)E * 4;
    int* bsum     = (int*)w;   w += 64 * 4;
    int* gstart   = (int*)w;   w += (size_t)(NGRAPH + 1) * 4;

    int nb = (N + 1023) / 1024;   // 49

    k_pad   <<<(N * DP + 255) / 256, 256, 0, stream>>>(x, xpad, cnt, N);
    k_count <<<(E + 255) / 256, 256, 0, stream>>>(dst, cnt, E);
    k_bsum  <<<nb, 256, 0, stream>>>(cnt, bsum, N);
    k_scan2 <<<nb, 256, 0, stream>>>(cnt, bsum, row_off, cursor, dinv, nb, N);
    k_fill  <<<(E + 255) / 256, 256, 0, stream>>>(src, dst, cursor, dinv, ssrc, ssw, E);
    k_gstart<<<2, 256, 0, stream>>>(batch, gstart, N);

    int jobs = (N >> 2) * 17;
    int grid_mm = 2 * ((jobs + 255) / 256);

    k_mm    <<<grid_mm, 256, 0, stream>>>(xpad, W1, bufA, N);
    k_agg   <<<(N * NCG + 255) / 256, 256, 0, stream>>>(bufA, b1, row_off, ssrc, ssw, dinv, bufB, N);
    k_mm    <<<grid_mm, 256, 0, stream>>>(bufB, W2, bufA, N);
    k_agg   <<<(N * NCG + 255) / 256, 256, 0, stream>>>(bufA, b2, row_off, ssrc, ssw, dinv, bufB, N);
    k_pool  <<<NGRAPH, 192, 0, stream>>>(bufB, gstart, out);
}

// Round 4
// 439.557 us; speedup vs baseline: 1.7855x; 1.1378x over previous
//
#include <hip/hip_runtime.h>

#define D 133
#define DP 136        // fp32 row stride (floats), 16B-aligned rows
#define DPB 160       // bf16 row stride (ushorts): 320 B = 5 full cache lines, 64B-aligned
#define NCGB 17       // bf16 column groups of 8 (covers 136)
#define NGRAPH 256
#define WS 72         // LDS stride (cols) per k-row of W half
#define HALF_COLS 68  // columns per k_mm half

__device__ __forceinline__ void fma4(float4& a, float s, const float4& w) {
    a.x = fmaf(s, w.x, a.x);
    a.y = fmaf(s, w.y, a.y);
    a.z = fmaf(s, w.z, a.z);
    a.w = fmaf(s, w.w, a.w);
}

__device__ __forceinline__ unsigned short f2bf(float x) {   // RNE
    unsigned int u = __float_as_uint(x);
    u += 0x7fffu + ((u >> 16) & 1u);
    return (unsigned short)(u >> 16);
}

__device__ __forceinline__ void cvt8(uint4 v, float* f) {
    f[0] = __uint_as_float(v.x << 16);
    f[1] = __uint_as_float(v.x & 0xffff0000u);
    f[2] = __uint_as_float(v.y << 16);
    f[3] = __uint_as_float(v.y & 0xffff0000u);
    f[4] = __uint_as_float(v.z << 16);
    f[5] = __uint_as_float(v.z & 0xffff0000u);
    f[6] = __uint_as_float(v.w << 16);
    f[7] = __uint_as_float(v.w & 0xffff0000u);
}

// ---------- pad x into stride-DP buffer, zero cnt ----------
__global__ void k_pad(const float* __restrict__ x, float* __restrict__ xpad,
                      int* __restrict__ cnt, int N) {
    int i = blockIdx.x * 256 + threadIdx.x;
    int total = N * DP;
    if (i < total) {
        int m = i / DP, c = i - m * DP;
        xpad[i] = (c < D) ? x[(size_t)m * D + c] : 0.f;
    }
    if (i < N) cnt[i] = 0;
}

// ---------- in-degree histogram (real edges only) ----------
__global__ void k_count(const int* __restrict__ dst, int* __restrict__ cnt, int E) {
    int i = blockIdx.x * 256 + threadIdx.x;
    if (i < E) atomicAdd(&cnt[dst[i]], 1);
}

// ---------- phase A: per-1024-chunk block sums ----------
__global__ __launch_bounds__(256) void k_bsum(const int* __restrict__ cnt,
                                              int* __restrict__ bsum, int N) {
    __shared__ int wsum[4];
    int b = blockIdx.x, t = threadIdx.x;
    int i0 = b * 1024 + t * 4;
    int s = 0;
    #pragma unroll
    for (int j = 0; j < 4; ++j) { int i = i0 + j; if (i < N) s += cnt[i]; }
    #pragma unroll
    for (int off = 32; off >= 1; off >>= 1) s += __shfl_down(s, off, 64);
    if ((t & 63) == 0) wsum[t >> 6] = s;
    __syncthreads();
    if (t == 0) bsum[b] = wsum[0] + wsum[1] + wsum[2] + wsum[3];
}

// ---------- phase B+C: base via wave-reduce over bsum, in-block scan ----------
__global__ __launch_bounds__(256) void k_scan2(const int* __restrict__ cnt,
                                               const int* __restrict__ bsum,
                                               int* __restrict__ row_off,
                                               int* __restrict__ cursor,
                                               float* __restrict__ dinv,
                                               int nb, int N) {
    __shared__ int base_s;
    __shared__ int scan[256];
    int b = blockIdx.x, t = threadIdx.x;
    if (t < 64) {
        int v = (t < b && t < nb) ? bsum[t] : 0;   // nb <= 64
        #pragma unroll
        for (int off = 32; off >= 1; off >>= 1) v += __shfl_down(v, off, 64);
        if (t == 0) base_s = v;
    }
    int i0 = b * 1024 + t * 4;
    int c0 = 0, c1 = 0, c2 = 0, c3 = 0;
    if (i0 + 3 < N) { c0 = cnt[i0]; c1 = cnt[i0+1]; c2 = cnt[i0+2]; c3 = cnt[i0+3]; }
    else {
        if (i0 < N) c0 = cnt[i0];
        if (i0 + 1 < N) c1 = cnt[i0+1];
        if (i0 + 2 < N) c2 = cnt[i0+2];
        if (i0 + 3 < N) c3 = cnt[i0+3];
    }
    int s = c0 + c1 + c2 + c3;
    scan[t] = s;
    __syncthreads();
    for (int off = 1; off < 256; off <<= 1) {
        int v = (t >= off) ? scan[t - off] : 0;
        __syncthreads();
        scan[t] += v;
        __syncthreads();
    }
    int excl = base_s + scan[t] - s;
    int cc[4] = {c0, c1, c2, c3};
    #pragma unroll
    for (int j = 0; j < 4; ++j) {
        int idx = i0 + j;
        if (idx < N) {
            row_off[idx] = excl;
            cursor[idx]  = excl;
            dinv[idx] = rsqrtf((float)(cc[j] + 1));
            excl += cc[j];
            if (idx == N - 1) row_off[N] = excl;
        }
    }
}

// ---------- scatter edges into CSR slots as (src, dinv[src]) records ----------
__global__ void k_fill(const int* __restrict__ src, const int* __restrict__ dst,
                       int* __restrict__ cursor, const float* __restrict__ dinv,
                       int2* __restrict__ earr, int E) {
    int i = blockIdx.x * 256 + threadIdx.x;
    if (i < E) {
        int s = src[i];
        int slot = atomicAdd(&cursor[dst[i]], 1);
        earr[slot] = make_int2(s, __float_as_int(dinv[s]));
    }
}

// ---------- graph boundary via binary search (batch is sorted) ----------
__global__ void k_gstart(const int* __restrict__ batch, int* __restrict__ gstart, int N) {
    int g = blockIdx.x * 256 + threadIdx.x;
    if (g > NGRAPH) return;
    int lo = 0, hi = N;
    while (lo < hi) {
        int mid = (lo + hi) >> 1;
        if (batch[mid] < g) lo = mid + 1; else hi = mid;
    }
    gstart[g] = lo;
}

// ---------- Y[m,n] = sum_k X[m,k]*W[k,n]; 4x4 tile per thread; bf16 output ----------
__global__ __launch_bounds__(256) void k_mm(const float* __restrict__ X,
                                            const float* __restrict__ W,
                                            unsigned short* __restrict__ Y, int N) {
    __shared__ float WL[DP * WS];            // 136*72*4 = 38.25 KB
    int half = blockIdx.x & 1;
    int cbase = half * HALF_COLS;
    for (int i = threadIdx.x; i < DP * HALF_COLS; i += 256) {
        int k = i / HALF_COLS;
        int cl = i - k * HALF_COLS;
        int c = cbase + cl;
        WL[k * WS + cl] = (k < D && c < D) ? W[(size_t)k * D + c] : 0.f;
    }
    __syncthreads();

    int rows4 = N >> 2;
    int jobs = rows4 * 17;
    int jid = (blockIdx.x >> 1) * 256 + threadIdx.x;
    if (jid >= jobs) return;
    int cg = jid % 17;
    int rg = jid / 17;
    int c0 = cg << 2;            // local col within half
    size_t mb = (size_t)(rg << 2);

    const float4* x0 = (const float4*)(X + mb * DP);
    const float4* x1 = x0 + (DP >> 2);
    const float4* x2 = x1 + (DP >> 2);
    const float4* x3 = x2 + (DP >> 2);

    float4 a0 = {0,0,0,0}, a1 = {0,0,0,0}, a2 = {0,0,0,0}, a3 = {0,0,0,0};
    const float* wp = WL + c0;
    #pragma unroll 2
    for (int k4 = 0; k4 < (DP >> 2); ++k4) {
        float4 v0 = x0[k4], v1 = x1[k4], v2 = x2[k4], v3 = x3[k4];
        float4 wA = *(const float4*)(wp + (k4 * 4 + 0) * WS);
        float4 wB = *(const float4*)(wp + (k4 * 4 + 1) * WS);
        float4 wC = *(const float4*)(wp + (k4 * 4 + 2) * WS);
        float4 wD = *(const float4*)(wp + (k4 * 4 + 3) * WS);
        fma4(a0, v0.x, wA); fma4(a0, v0.y, wB); fma4(a0, v0.z, wC); fma4(a0, v0.w, wD);
        fma4(a1, v1.x, wA); fma4(a1, v1.y, wB); fma4(a1, v1.z, wC); fma4(a1, v1.w, wD);
        fma4(a2, v2.x, wA); fma4(a2, v2.y, wB); fma4(a2, v2.z, wC); fma4(a2, v2.w, wD);
        fma4(a3, v3.x, wA); fma4(a3, v3.y, wB); fma4(a3, v3.z, wC); fma4(a3, v3.w, wD);
    }
    size_t o = mb * DPB + cbase + c0;        // ushort units; 8B-aligned stores
    ushort4 s0 = {f2bf(a0.x), f2bf(a0.y), f2bf(a0.z), f2bf(a0.w)};
    ushort4 s1 = {f2bf(a1.x), f2bf(a1.y), f2bf(a1.z), f2bf(a1.w)};
    ushort4 s2 = {f2bf(a2.x), f2bf(a2.y), f2bf(a2.z), f2bf(a2.w)};
    ushort4 s3 = {f2bf(a3.x), f2bf(a3.y), f2bf(a3.z), f2bf(a3.w)};
    *(ushort4*)(Y + o)           = s0;
    *(ushort4*)(Y + o + DPB)     = s1;
    *(ushort4*)(Y + o + 2 * DPB) = s2;
    *(ushort4*)(Y + o + 3 * DPB) = s3;
}

// ---------- normalized aggregation + bias + relu (bf16 gather, fp32 accumulate) ----------
__global__ __launch_bounds__(256) void k_agg(const unsigned short* __restrict__ H,
                                             const float* __restrict__ bias,
                                             const int* __restrict__ row_off,
                                             const int2* __restrict__ earr,
                                             const float* __restrict__ dinv,
                                             float* __restrict__ out, int N) {
    int idx = blockIdx.x * 256 + threadIdx.x;
    if (idx >= N * NCGB) return;
    int node = idx / NCGB;
    int cg = idx - node * NCGB;
    int c = cg << 3;
    float di = dinv[node];
    float acc[8], f[8];
    uint4 hv = *(const uint4*)(H + (size_t)node * DPB + c);
    cvt8(hv, f);
    #pragma unroll
    for (int j = 0; j < 8; ++j) acc[j] = di * f[j];
    int e = row_off[node], e1 = row_off[node + 1];
    for (; e + 4 <= e1; e += 4) {
        int2 r0 = earr[e], r1 = earr[e+1], r2 = earr[e+2], r3 = earr[e+3];
        uint4 v0 = *(const uint4*)(H + (size_t)r0.x * DPB + c);
        uint4 v1 = *(const uint4*)(H + (size_t)r1.x * DPB + c);
        uint4 v2 = *(const uint4*)(H + (size_t)r2.x * DPB + c);
        uint4 v3 = *(const uint4*)(H + (size_t)r3.x * DPB + c);
        float w0 = __int_as_float(r0.y), w1 = __int_as_float(r1.y);
        float w2 = __int_as_float(r2.y), w3 = __int_as_float(r3.y);
        cvt8(v0, f);
        #pragma unroll
        for (int j = 0; j < 8; ++j) acc[j] = fmaf(w0, f[j], acc[j]);
        cvt8(v1, f);
        #pragma unroll
        for (int j = 0; j < 8; ++j) acc[j] = fmaf(w1, f[j], acc[j]);
        cvt8(v2, f);
        #pragma unroll
        for (int j = 0; j < 8; ++j) acc[j] = fmaf(w2, f[j], acc[j]);
        cvt8(v3, f);
        #pragma unroll
        for (int j = 0; j < 8; ++j) acc[j] = fmaf(w3, f[j], acc[j]);
    }
    for (; e < e1; ++e) {
        int2 r = earr[e];
        uint4 v = *(const uint4*)(H + (size_t)r.x * DPB + c);
        float wv = __int_as_float(r.y);
        cvt8(v, f);
        #pragma unroll
        for (int j = 0; j < 8; ++j) acc[j] = fmaf(wv, f[j], acc[j]);
    }
    float b[8];
    #pragma unroll
    for (int j = 0; j < 8; ++j) b[j] = (c + j < D) ? bias[c + j] : 0.f;
    float4 o0, o1;
    o0.x = fmaxf(fmaf(di, acc[0], b[0]), 0.f);
    o0.y = fmaxf(fmaf(di, acc[1], b[1]), 0.f);
    o0.z = fmaxf(fmaf(di, acc[2], b[2]), 0.f);
    o0.w = fmaxf(fmaf(di, acc[3], b[3]), 0.f);
    o1.x = fmaxf(fmaf(di, acc[4], b[4]), 0.f);
    o1.y = fmaxf(fmaf(di, acc[5], b[5]), 0.f);
    o1.z = fmaxf(fmaf(di, acc[6], b[6]), 0.f);
    o1.w = fmaxf(fmaf(di, acc[7], b[7]), 0.f);
    *(float4*)(out + (size_t)node * DP + c)     = o0;
    *(float4*)(out + (size_t)node * DP + c + 4) = o1;
}

// ---------- per-graph mean pool (one block per graph) ----------
__global__ void k_pool(const float* __restrict__ H, const int* __restrict__ gstart,
                       float* __restrict__ out) {
    int g = blockIdx.x;
    int t = threadIdx.x;
    if (t >= D) return;
    int s = gstart[g], e = gstart[g + 1];
    float acc = 0.f;
    for (int i = s; i < e; ++i) acc += H[(size_t)i * DP + t];
    float n = (float)(e - s);
    out[(size_t)g * D + t] = acc / fmaxf(n, 1.f);
}

extern "C" void kernel_launch(void* const* d_in, const int* in_sizes, int n_in,
                              void* d_out, int out_size, void* d_ws, size_t ws_size,
                              hipStream_t stream) {
    const float* x   = (const float*)d_in[0];
    const int* ei    = (const int*)d_in[1];
    const int* batch = (const int*)d_in[2];
    const float* W1  = (const float*)d_in[3];
    const float* b1  = (const float*)d_in[4];
    const float* W2  = (const float*)d_in[5];
    const float* b2  = (const float*)d_in[6];
    float* out = (float*)d_out;

    int N = in_sizes[0] / D;   // 50000
    int E = in_sizes[1] / 2;   // 800000
    const int* src = ei;
    const int* dst = ei + E;

    char* w = (char*)d_ws;
    float* xpad          = (float*)w;          w += (size_t)N * DP * 4;
    float* bufA          = (float*)w;          w += (size_t)N * DP * 4;
    unsigned short* Hb   = (unsigned short*)w; w += (size_t)N * DPB * 2;
    float* dinv          = (float*)w;          w += (size_t)N * 4;
    int* cnt             = (int*)w;            w += (size_t)N * 4;
    int* row_off         = (int*)w;            w += (size_t)(N + 1) * 4;
    int* cursor          = (int*)w;            w += (size_t)N * 4;
    int2* earr           = (int2*)w;           w += (size_t)E * 8;
    int* bsum            = (int*)w;            w += 64 * 4;
    int* gstart          = (int*)w;            w += (size_t)(NGRAPH + 1) * 4;

    int nb = (N + 1023) / 1024;   // 49

    k_pad   <<<(N * DP + 255) / 256, 256, 0, stream>>>(x, xpad, cnt, N);
    k_count <<<(E + 255) / 256, 256, 0, stream>>>(dst, cnt, E);
    k_bsum  <<<nb, 256, 0, stream>>>(cnt, bsum, N);
    k_scan2 <<<nb, 256, 0, stream>>>(cnt, bsum, row_off, cursor, dinv, nb, N);
    k_fill  <<<(E + 255) / 256, 256, 0, stream>>>(src, dst, cursor, dinv, earr, E);
    k_gstart<<<2, 256, 0, stream>>>(batch, gstart, N);

    int jobs = (N >> 2) * 17;
    int grid_mm = 2 * ((jobs + 255) / 256);
    int grid_agg = (N * NCGB + 255) / 256;

    k_mm    <<<grid_mm, 256, 0, stream>>>(xpad, W1, Hb, N);
    k_agg   <<<grid_agg, 256, 0, stream>>>(Hb, b1, row_off, earr, dinv, bufA, N);
    k_mm    <<<grid_mm, 256, 0, stream>>>(bufA, W2, Hb, N);
    k_agg   <<<grid_agg, 256, 0, stream>>>(Hb, b2, row_off, earr, dinv, bufA, N);
    k_pool  <<<NGRAPH, 192, 0, stream>>>(bufA, gstart, out);
}